// Round 1
// baseline (250.328 us; speedup 1.0000x reference)
//
#include <hip/hip_runtime.h>
#include <stdint.h>

// RNN: h_{t+1} = tanh(x_t @ W_ih^T + b_ih + b_hh + h_t @ W_hh^T), out = h_T @ fc_w^T + fc_b
// B=8192, T=512, IN=8, H=16.
//
// Mapping: 16 lanes per batch element (lane j owns hidden unit j). 256-thread block
// = 16 batch elements. Grid = 512 blocks (2 blocks/CU, 8 waves/CU, 2 waves/SIMD).
//
// KEY CHANGE vs previous version: h exchange is done entirely in-register with a
// DPP row_ror butterfly ({8,4,2,1} => 15 v_mov_b32_dpp, dep depth 4, VALU-only).
// DPP "rows" are 16 lanes on CDNA and our groups are 16-lane aligned. This removes
// the per-step LDS round-trip (~120+ cyc ds_write->ds_read) from the recurrence and
// all hbuf bank conflicts. The rotate direction convention is made irrelevant by
// calibration: we run the identical butterfly on the lane index j at init and load
// W_hh row j permuted to match (whh[m] pairs with gathered value v[m]).
//
// Secondary: x staging is double-buffered via global_load_lds (16B/lane, async),
// issued at tile start so HBM latency hides under 32 steps of compute; one barrier
// per tile (the compiler's vmcnt(0)+s_barrier drain is exactly the fence we need).

#define RNN_B   8192
#define RNN_T   512
#define RNN_IN  8
#define RNN_H   16
#define TC      32                 // timesteps per x tile
#define NB      16                 // batch elements per block
#define XSTRIDE 264                // padded floats per xs row (TC*IN=256 +8 pad -> groups bank-disjoint)
#define NTILE   (RNN_T / TC)
#define BUFSZ   (NB * XSTRIDE)

// DPP row_ror:N within 16-lane rows. Prefer mov_dpp (no tied 'old' operand -> no
// init mov); fall back to update_dpp. All lanes active & all sources valid here,
// so bound_ctrl/old don't matter semantically.
#if defined(__has_builtin)
#if __has_builtin(__builtin_amdgcn_mov_dpp)
#define ROR16(x, N) ((uint32_t)__builtin_amdgcn_mov_dpp((int)(x), 0x120 + (N), 0xF, 0xF, false))
#endif
#endif
#ifndef ROR16
#define ROR16(x, N) ((uint32_t)__builtin_amdgcn_update_dpp(0, (int)(x), 0x120 + (N), 0xF, 0xF, false))
#endif

// Butterfly all-gather across a 16-lane row: v[m] = value of lane (row-rotate^m of self).
// Composition of rotations is additive, so v[m]'s source lane = self (+/-) m mod 16,
// with the sign fixed by HW convention -- calibrated away at init (see sv[] below).
__device__ __forceinline__ void gather16(uint32_t in, uint32_t v[16]) {
    v[0]  = in;
    v[8]  = ROR16(v[0], 8);
    v[4]  = ROR16(v[0], 4);
    v[12] = ROR16(v[8], 4);
    v[2]  = ROR16(v[0], 2);
    v[6]  = ROR16(v[4], 2);
    v[10] = ROR16(v[8], 2);
    v[14] = ROR16(v[12], 2);
    v[1]  = ROR16(v[0], 1);
    v[3]  = ROR16(v[2], 1);
    v[5]  = ROR16(v[4], 1);
    v[7]  = ROR16(v[6], 1);
    v[9]  = ROR16(v[8], 1);
    v[11] = ROR16(v[10], 1);
    v[13] = ROR16(v[12], 1);
    v[15] = ROR16(v[14], 1);
}

// Stage one 16-row x 32-timestep x-tile into LDS via async global_load_lds.
// Wave wv, p=0..3 -> row = wv + 4p (wave-uniform LDS base); HW writes lane*16B,
// which matches the row's 256 contiguous floats exactly. Row base = row*1056 B
// (16B aligned); global src = per-lane, contiguous 16B.
__device__ __forceinline__ void stage_tile(const float* __restrict__ x,
                                           float* lds_base, int b0, int t0,
                                           int wv, int lane)
{
#pragma unroll
    for (int p = 0; p < 4; ++p) {
        const int row = wv + 4 * p;
        const float* gp = x + ((size_t)(b0 + row) * RNN_T + t0) * RNN_IN + lane * 4;
        float* lp = lds_base + row * XSTRIDE;
        __builtin_amdgcn_global_load_lds(
            (const __attribute__((address_space(1))) uint32_t*)gp,
            (__attribute__((address_space(3))) uint32_t*)lp,
            16, 0, 0);
    }
}

__global__ __launch_bounds__(256, 2) void rnn_fused_kernel(
    const float* __restrict__ x,     // [B, T, IN]
    const float* __restrict__ W_ih,  // [H, IN]
    const float* __restrict__ W_hh,  // [H, H]
    const float* __restrict__ b_ih,  // [H]
    const float* __restrict__ b_hh,  // [H]
    const float* __restrict__ fc_w,  // [1, H]
    const float* __restrict__ fc_b,  // [1]
    float* __restrict__ out)         // [B, 1]
{
    __shared__ float xs[2 * BUFSZ];  // double-buffered x tiles (33 KB)

    const int tid  = (int)threadIdx.x;
    const int j    = tid & 15;           // hidden unit
    const int g    = tid >> 4;           // group (batch element) within block
    const int wv   = tid >> 6;           // wave within block
    const int lane = tid & 63;
    const int b0   = (int)blockIdx.x * NB;
    const int b    = b0 + g;

    // --- calibrate the gather: run the butterfly on j itself; sv[m] = hidden index
    // whose h value lands in v[m] on this lane. Then pre-permute W_hh row j so
    // whh[m] multiplies v[m]. Direction/convention-proof by construction.
    uint32_t sv[16];
    gather16((uint32_t)j, sv);
    float whh[RNN_H];
#pragma unroll
    for (int m = 0; m < 16; ++m) whh[m] = W_hh[j * RNN_H + (int)sv[m]];

    float wih[RNN_IN];
#pragma unroll
    for (int i = 0; i < RNN_IN; i += 4) {
        float4 w = *(const float4*)(W_ih + j * RNN_IN + i);
        wih[i] = w.x; wih[i+1] = w.y; wih[i+2] = w.z; wih[i+3] = w.w;
    }
    const float bias = b_ih[j] + b_hh[j];

    // prologue: stage tile 0 into buffer 0
    stage_tile(x, xs, b0, 0, wv, lane);
    __syncthreads();   // vmcnt(0) drain + barrier: tile 0 resident

    float hn = 0.0f;

    for (int tile = 0; tile < NTILE; ++tile) {
        const int cur = tile & 1;
        // issue next tile's async loads now; they complete during the 32-step compute
        // and are drained by the end-of-tile barrier. Writes go to the other buffer,
        // which no wave reads this tile (last read was tile-1, fenced by its barrier).
        if (tile + 1 < NTILE)
            stage_tile(x, xs + (cur ^ 1) * BUFSZ, b0, (tile + 1) * TC, wv, lane);

        const float* xg = xs + cur * BUFSZ + g * XSTRIDE;

#pragma unroll 8
        for (int tt = 0; tt < TC; ++tt) {
            const float* xp = xg + tt * RNN_IN;
            const float4 xa = *(const float4*)(xp);      // broadcast within group;
            const float4 xb = *(const float4*)(xp + 4);  // groups 8 banks apart -> no conflict

            // in-register all-gather of h across the 16-lane group (VALU only)
            uint32_t v[16];
            gather16(__float_as_uint(hn), v);

            // 4 independent accumulator chains
            float a0 = fmaf(wih[0], xa.x, bias);
            a0 = fmaf(wih[1], xa.y, a0);
            a0 = fmaf(wih[2], xa.z, a0);
            a0 = fmaf(wih[3], xa.w, a0);
            a0 = fmaf(whh[0], __uint_as_float(v[0]), a0);
            a0 = fmaf(whh[1], __uint_as_float(v[1]), a0);
            a0 = fmaf(whh[2], __uint_as_float(v[2]), a0);
            a0 = fmaf(whh[3], __uint_as_float(v[3]), a0);

            float a1 = wih[4] * xb.x;
            a1 = fmaf(wih[5], xb.y, a1);
            a1 = fmaf(wih[6], xb.z, a1);
            a1 = fmaf(wih[7], xb.w, a1);
            a1 = fmaf(whh[4], __uint_as_float(v[4]), a1);
            a1 = fmaf(whh[5], __uint_as_float(v[5]), a1);
            a1 = fmaf(whh[6], __uint_as_float(v[6]), a1);
            a1 = fmaf(whh[7], __uint_as_float(v[7]), a1);

            float a2 = whh[8] * __uint_as_float(v[8]);
            a2 = fmaf(whh[9],  __uint_as_float(v[9]),  a2);
            a2 = fmaf(whh[10], __uint_as_float(v[10]), a2);
            a2 = fmaf(whh[11], __uint_as_float(v[11]), a2);

            float a3 = whh[12] * __uint_as_float(v[12]);
            a3 = fmaf(whh[13], __uint_as_float(v[13]), a3);
            a3 = fmaf(whh[14], __uint_as_float(v[14]), a3);
            a3 = fmaf(whh[15], __uint_as_float(v[15]), a3);

            const float s = (a0 + a2) + (a1 + a3);

            // tanh(s) = 1 - 2/(exp2(s*2*log2e)+1); saturates correctly at +/-inf
            const float e  = __builtin_amdgcn_exp2f(s * 2.8853900817779268f);
            const float r  = __builtin_amdgcn_rcpf(e + 1.0f);
            hn = fmaf(-2.0f, r, 1.0f);
        }
        __syncthreads();   // drains next-tile loads (issued a full tile ago) + sync readers
    }

    // --- epilogue: out[b] = sum_j fc_w[j] * h_j + fc_b ---
    float vsum = hn * fc_w[j];
    vsum += __shfl_xor(vsum, 1);
    vsum += __shfl_xor(vsum, 2);
    vsum += __shfl_xor(vsum, 4);
    vsum += __shfl_xor(vsum, 8);
    if (j == 0) out[b] = vsum + fc_b[0];
}

extern "C" void kernel_launch(void* const* d_in, const int* in_sizes, int n_in,
                              void* d_out, int out_size, void* d_ws, size_t ws_size,
                              hipStream_t stream)
{
    const float* x    = (const float*)d_in[0];
    const float* W_ih = (const float*)d_in[1];
    const float* W_hh = (const float*)d_in[2];
    const float* b_ih = (const float*)d_in[3];
    const float* b_hh = (const float*)d_in[4];
    const float* fc_w = (const float*)d_in[5];
    const float* fc_b = (const float*)d_in[6];
    float* out = (float*)d_out;

    dim3 grid(RNN_B / NB);   // 512 blocks
    dim3 block(256);
    rnn_fused_kernel<<<grid, block, 0, stream>>>(x, W_ih, W_hh, b_ih, b_hh, fc_w, fc_b, out);
}